// Round 5
// baseline (10613.751 us; speedup 1.0000x reference)
//
#include <hip/hip_runtime.h>
#include <math.h>

// ---------------------------------------------------------------------------
// SRRNN: state-regularized GRU.  B=64, S=512, I=256, H=512, K=256, TEMP=1.
//
// Round 5: R4's overlap structure + R1's PROVEN agent-scope primitives.
//  - Gate weights in registers (12 float4/thread): waves 0-3 hold W_ih slice,
//    waves 4-7 hold SWT slice (SWT = W_hh @ states^T; gh_{t+1} = p_t @ SWT^T).
//  - Groups by blockIdx: g = bid>>5, cu = bid&31. 84KB LDS -> 1 block/CU ->
//    all 256 blocks co-resident (proven in R1).
//  - ALL cross-CU traffic via __hip_atomic_* agent-scope scalar ops (R1's
//    exact passing mechanism). No sc0/buffer_inv hand-rolled asm.
//  - Flag barriers: monotone per-step values, memset-zeroed each launch.
//  - Overlap: x(t+1) staging + gi(t+1) GEMM under barrier-1 shadow;
//    gh(t+1) GEMM (waves 4-7) concurrent with h_new (waves 0-3).
// ---------------------------------------------------------------------------

#define B_ 64
#define S_ 512
#define I_ 256
#define H_ 512
#define K_ 256
#define G3H 1536
#define NG 8
#define GC 32
#define GB 8
#define TPB 512
#define SPIN_MAX (1 << 14)

// workspace layout (bytes)
#define WS_FLAGS 0                                     // [8][2][32] u32 = 2048
#define WS_MEMSET_SZ 2048
#define WS_SWT 4096
#define WS_SWT_SZ (G3H * K_ * 4)
#define WS_GH0 (WS_SWT + WS_SWT_SZ)
#define WS_GH0_SZ (B_ * G3H * 4)
#define WS_DPART (WS_GH0 + WS_GH0_SZ)
#define WS_DPART_SZ (NG * GC * GB * K_ * 4)
#define WS_DRED (WS_DPART + WS_DPART_SZ)
#define WS_DRED_SZ (NG * GB * K_ * 4)

#define SMEM_BYTES 86016   // 84KB: forces 1 block/CU

// LDS float offsets
#define L_SSL 0            // swizzled states slice, 5224 floats
#define L_XCH 5224         // x chunked  [8][16][20]
#define L_PCH 7784         // p chunked  [8][16][20]
#define L_DSL 10344        // d flat     [8][256]
#define L_GI 12392         // [8][48]
#define L_GH 12776         // [8][48]
#define L_HC 13160         // [8][16]
#define L_HP 13288         // [8][16]
#define L_BIH 13416        // [48]
#define L_BHH 13464        // [48]

#define SADDR(k) ((k) * 20 + (((k) >> 6) << 3))

#define OUT_OFF_HN (B_ * S_ * H_)
#define OUT_OFF_P (OUT_OFF_HN + B_ * H_)

#define AGENT __HIP_MEMORY_SCOPE_AGENT
#define RLX __ATOMIC_RELAXED

// ---------------------------------------------------------------------------
__global__ void kernel_swt(const float* __restrict__ Whh,
                           const float* __restrict__ states,
                           float* __restrict__ SWT) {
  int r0 = blockIdx.x * 8;
  int k = threadIdx.x;  // 0..255
  const float* sr = states + (size_t)k * H_;
  float acc[8];
#pragma unroll
  for (int q = 0; q < 8; ++q) acc[q] = 0.f;
  for (int j = 0; j < H_; ++j) {
    float sv = sr[j];
#pragma unroll
    for (int q = 0; q < 8; ++q) acc[q] += Whh[(size_t)(r0 + q) * H_ + j] * sv;
  }
#pragma unroll
  for (int q = 0; q < 8; ++q) SWT[(size_t)(r0 + q) * K_ + k] = acc[q];
}

__global__ void kernel_gh0(const float* __restrict__ Whh,
                           const float* __restrict__ h0,
                           float* __restrict__ Gh0) {
  int b = blockIdx.x;
  int tid = threadIdx.x;  // 256
  __shared__ float h[H_];
  for (int e = tid; e < H_; e += 256) h[e] = h0[(size_t)b * H_ + e];
  __syncthreads();
  for (int r = tid; r < G3H; r += 256) {
    const float* wr = Whh + (size_t)r * H_;
    float acc = 0.f;
    for (int j = 0; j < H_; ++j) acc += wr[j] * h[j];
    Gh0[(size_t)b * G3H + r] = acc;
  }
}

// ---------------------------------------------------------------------------
#define DOT16(wA, wB, wC, wD)                                         \
  (wA.x * x0.x + wA.y * x0.y + wA.z * x0.z + wA.w * x0.w +            \
   wB.x * x1.x + wB.y * x1.y + wB.z * x1.z + wB.w * x1.w +            \
   wC.x * x2.x + wC.y * x2.y + wC.z * x2.z + wC.w * x2.w +            \
   wD.x * x3.x + wD.y * x3.y + wD.z * x3.z + wD.w * x3.w)

__device__ __forceinline__ void gemm48(const float* inb, float* outb,
                                       const float4* wreg, int kseg, int r48b) {
  float acc[3][8];
#pragma unroll
  for (int b = 0; b < 8; ++b) {
    const float4* xc = (const float4*)(inb + (b * 16 + kseg) * 20);
    float4 x0 = xc[0], x1 = xc[1], x2 = xc[2], x3 = xc[3];
#pragma unroll
    for (int j = 0; j < 3; ++j)
      acc[j][b] = DOT16(wreg[j * 4 + 0], wreg[j * 4 + 1],
                        wreg[j * 4 + 2], wreg[j * 4 + 3]);
  }
#pragma unroll
  for (int j = 0; j < 3; ++j)
#pragma unroll
    for (int b = 0; b < 8; ++b) {
      float v = acc[j][b];
      v += __shfl_xor(v, 1);
      v += __shfl_xor(v, 2);
      v += __shfl_xor(v, 4);
      v += __shfl_xor(v, 8);
      acc[j][b] = v;
    }
  if (kseg < 8) {
#pragma unroll
    for (int b = 0; b < 8; ++b)
      if (kseg == b) {
#pragma unroll
        for (int j = 0; j < 3; ++j) outb[b * 48 + r48b + j] = acc[j][b];
      }
  }
}

// ---------------------------------------------------------------------------
__global__ __launch_bounds__(TPB) void srrnn_main(
    const float* __restrict__ input, const float* __restrict__ h0,
    const float* __restrict__ W_ih, const float* __restrict__ bias_ih,
    const float* __restrict__ bias_hh, const float* __restrict__ states,
    const float* __restrict__ SWT, const float* __restrict__ Gh0,
    float* __restrict__ dpart, float* __restrict__ dred,
    unsigned int* flags,
    float* __restrict__ out, float* __restrict__ hn,
    float* __restrict__ probs) {
  const int tid = threadIdx.x;
  const int g = blockIdx.x >> 5;
  const int cu = blockIdx.x & 31;
  unsigned* fl = flags + g * 64;  // [2][32]

  extern __shared__ float smem[];
  float* s_sl = smem + L_SSL;
  float* x_ch = smem + L_XCH;
  float* p_ch = smem + L_PCH;
  float* d_sl = smem + L_DSL;
  float* gi_sl = smem + L_GI;
  float* gh_sl = smem + L_GH;
  float* hc_sl = smem + L_HC;
  float* hp_sl = smem + L_HP;
  float* bih_sl = smem + L_BIH;
  float* bhh_sl = smem + L_BHH;

  const int wg = tid >> 6;    // wave 0..7
  const int lane = tid & 63;
  const int rfrag = lane >> 4;
  const int kseg = lane & 15;
  const int m = wg >> 2;                       // 0: gi+h_new waves, 1: gh waves
  const int r48b = (wg & 3) * 12 + rfrag * 3;

  // ---- setup ----
  for (int e = tid; e < K_ * 16; e += TPB) {
    int k = e >> 4, d = e & 15;
    s_sl[SADDR(k) + d] = states[((size_t)k << 9) + (cu << 4) + d];
  }
  if (tid < 48) {
    int grow = ((tid >> 4) << 9) + (cu << 4) + (tid & 15);
    bih_sl[tid] = bias_ih[grow];
    bhh_sl[tid] = bias_hh[grow];
  }
  if (tid < 128) {
    int b = tid >> 4, d = tid & 15;
    hp_sl[tid] = h0[((size_t)(g * GB + b) << 9) + (cu << 4) + d];
  }
  if (tid < 384) {
    int b = tid / 48, r = tid % 48;
    int grow = ((r >> 4) << 9) + (cu << 4) + (r & 15);
    gh_sl[b * 48 + r] = Gh0[(size_t)(g * GB + b) * G3H + grow];
  }
  float4 wreg[12];
  {
    const float* Wsrc = m ? SWT : W_ih;
#pragma unroll
    for (int j = 0; j < 3; ++j) {
      int rr = r48b + j;
      int grow = ((rr >> 4) << 9) + (cu << 4) + (rr & 15);
      const float4* src = (const float4*)(Wsrc + (size_t)grow * 256 + kseg * 16);
      wreg[j * 4 + 0] = src[0];
      wreg[j * 4 + 1] = src[1];
      wreg[j * 4 + 2] = src[2];
      wreg[j * 4 + 3] = src[3];
    }
  }

  // ---- pre-loop: stage x(0), gi(0) ----
  {
    int b = tid >> 6;
    const float4* src =
        (const float4*)(input + (((size_t)(g * GB + b) * S_) << 8)) + lane;
    float4 v = *src;
    int ks = lane >> 2, pos = lane & 3;
    *(float4*)(x_ch + (b * 16 + ks) * 20 + pos * 4) = v;
  }
  __syncthreads();
  if (m == 0) gemm48(x_ch, gi_sl, wreg, kseg, r48b);
  __syncthreads();

  for (int t = 0; t < S_; ++t) {
    // ---- A: gates + h_cand over owned 16 dims ----
    if (tid < 128) {
      int b = tid >> 4, d = tid & 15;
      float gir = gi_sl[b * 48 + d] + bih_sl[d];
      float giz = gi_sl[b * 48 + 16 + d] + bih_sl[16 + d];
      float gin = gi_sl[b * 48 + 32 + d] + bih_sl[32 + d];
      float ghr = gh_sl[b * 48 + d] + bhh_sl[d];
      float ghz = gh_sl[b * 48 + 16 + d] + bhh_sl[16 + d];
      float ghn = gh_sl[b * 48 + 32 + d] + bhh_sl[32 + d];
      float r = 1.f / (1.f + expf(-(gir + ghr)));
      float z = 1.f / (1.f + expf(-(giz + ghz)));
      float n = tanhf(gin + r * ghn);
      hc_sl[tid] = (1.f - z) * n + z * hp_sl[tid];
    }
    __syncthreads();

    // ---- B: partial squared distances (wave = batch), k = 4*lane+i ----
    {
      const float4* hp4 = (const float4*)(hc_sl + wg * 16);
      float4 hA = hp4[0], hB = hp4[1], hC = hp4[2], hD = hp4[3];
      int sb = SADDR(4 * lane);
      float dv0, dv1, dv2, dv3;
#define DIST16(i, dst)                                                \
      {                                                               \
        const float4* sr = (const float4*)(s_sl + sb + 20 * (i));     \
        float4 sA = sr[0], sB = sr[1], sC = sr[2], sD = sr[3];        \
        float e, a;                                                   \
        e = hA.x - sA.x; a = e * e;   e = hA.y - sA.y; a += e * e;    \
        e = hA.z - sA.z; a += e * e;  e = hA.w - sA.w; a += e * e;    \
        e = hB.x - sB.x; a += e * e;  e = hB.y - sB.y; a += e * e;    \
        e = hB.z - sB.z; a += e * e;  e = hB.w - sB.w; a += e * e;    \
        e = hC.x - sC.x; a += e * e;  e = hC.y - sC.y; a += e * e;    \
        e = hC.z - sC.z; a += e * e;  e = hC.w - sC.w; a += e * e;    \
        e = hD.x - sD.x; a += e * e;  e = hD.y - sD.y; a += e * e;    \
        e = hD.z - sD.z; a += e * e;  e = hD.w - sD.w; a += e * e;    \
        dst = a;                                                      \
      }
      DIST16(0, dv0); DIST16(1, dv1); DIST16(2, dv2); DIST16(3, dv3);
#undef DIST16
      float* dpb =
          dpart + ((((size_t)(g * GC + cu)) * GB + wg) << 8) + (lane << 2);
      __hip_atomic_store(dpb + 0, dv0, RLX, AGENT);
      __hip_atomic_store(dpb + 1, dv1, RLX, AGENT);
      __hip_atomic_store(dpb + 2, dv2, RLX, AGENT);
      __hip_atomic_store(dpb + 3, dv3, RLX, AGENT);
    }
    __syncthreads();  // drains vmcnt in every wave before the release store
    if (tid == 0)
      __hip_atomic_store(fl + cu, (unsigned)(t + 1), __ATOMIC_RELEASE, AGENT);

    // ---- D (barrier-1 shadow): stage x(t+1), gi(t+1) on waves 0-3 ----
    if (t + 1 < S_) {
      {
        int b = tid >> 6;
        const float4* src =
            (const float4*)(input +
                            (((size_t)(g * GB + b) * S_ + (t + 1)) << 8)) +
            lane;
        float4 v = *src;
        int ks = lane >> 2, pos = lane & 3;
        *(float4*)(x_ch + (b * 16 + ks) * 20 + pos * 4) = v;
      }
      __syncthreads();
      if (m == 0) gemm48(x_ch, gi_sl, wreg, kseg, r48b);
    }

    // ---- E: acquire barrier 1 ----
    if (tid < GC) {
      for (int it = 0; it < SPIN_MAX; ++it) {
        if (__hip_atomic_load(fl + tid, RLX, AGENT) >= (unsigned)(t + 1)) break;
        __builtin_amdgcn_s_sleep(1);
      }
    }
    __syncthreads();

    // ---- F: cross-CU reduce of own 8-k slice ----
    {
      int b = tid >> 6, kq2 = (lane >> 5), c = lane & 31;
      const float* q = dpart + ((((size_t)g * GC + c) * GB + b) << 8) +
                       (cu << 3) + (kq2 << 2);
      float s0 = __hip_atomic_load(q + 0, RLX, AGENT);
      float s1 = __hip_atomic_load(q + 1, RLX, AGENT);
      float s2 = __hip_atomic_load(q + 2, RLX, AGENT);
      float s3 = __hip_atomic_load(q + 3, RLX, AGENT);
#pragma unroll
      for (int off = 16; off >= 1; off >>= 1) {
        s0 += __shfl_xor(s0, off);
        s1 += __shfl_xor(s1, off);
        s2 += __shfl_xor(s2, off);
        s3 += __shfl_xor(s3, off);
      }
      if (c == 0) {
        float* w = dred + (((size_t)g * GB + b) << 8) + (cu << 3) + (kq2 << 2);
        __hip_atomic_store(w + 0, s0, RLX, AGENT);
        __hip_atomic_store(w + 1, s1, RLX, AGENT);
        __hip_atomic_store(w + 2, s2, RLX, AGENT);
        __hip_atomic_store(w + 3, s3, RLX, AGENT);
      }
    }
    __syncthreads();  // drains vmcnt before release
    if (tid == 0)
      __hip_atomic_store(fl + 32 + cu, (unsigned)(t + 1), __ATOMIC_RELEASE,
                         AGENT);

    // ---- G: acquire barrier 2, fetch d, softmax, p ----
    if (tid < GC) {
      for (int it = 0; it < SPIN_MAX; ++it) {
        if (__hip_atomic_load(fl + 32 + tid, RLX, AGENT) >= (unsigned)(t + 1))
          break;
        __builtin_amdgcn_s_sleep(1);
      }
    }
    __syncthreads();
    {
      const float* q = dred + ((size_t)g << 11) + (tid << 2);
      float a0 = __hip_atomic_load(q + 0, RLX, AGENT);
      float a1 = __hip_atomic_load(q + 1, RLX, AGENT);
      float a2 = __hip_atomic_load(q + 2, RLX, AGENT);
      float a3 = __hip_atomic_load(q + 3, RLX, AGENT);
      float* dst = d_sl + (tid << 2);
      dst[0] = a0; dst[1] = a1; dst[2] = a2; dst[3] = a3;
    }
    __syncthreads();
    {
      const float* db = d_sl + wg * K_;
      float d0 = db[lane], d1 = db[lane + 64], d2 = db[lane + 128],
            d3 = db[lane + 192];
      float mn = fminf(fminf(d0, d1), fminf(d2, d3));
#pragma unroll
      for (int off = 32; off >= 1; off >>= 1) mn = fminf(mn, __shfl_xor(mn, off));
      float e0 = expf(mn - d0), e1 = expf(mn - d1), e2 = expf(mn - d2),
            e3 = expf(mn - d3);
      float s = (e0 + e1) + (e2 + e3);
#pragma unroll
      for (int off = 32; off >= 1; off >>= 1) s += __shfl_xor(s, off);
      float inv = 1.f / s;
      e0 *= inv; e1 *= inv; e2 *= inv; e3 *= inv;
      int hi = lane >> 4, lo = lane & 15;
      p_ch[(wg * 16 + hi + 0) * 20 + lo] = e0;
      p_ch[(wg * 16 + hi + 4) * 20 + lo] = e1;
      p_ch[(wg * 16 + hi + 8) * 20 + lo] = e2;
      p_ch[(wg * 16 + hi + 12) * 20 + lo] = e3;
      if (cu == 0) {
        float* pr = probs + ((size_t)(g * GB + wg) * S_ + t) * K_;
        pr[lane] = e0; pr[lane + 64] = e1; pr[lane + 128] = e2; pr[lane + 192] = e3;
      }
    }
    __syncthreads();

    // ---- H: h_new on waves 0-3 (2 batches each) || gh(t+1) on waves 4-7 ----
    if (m == 0) {
#pragma unroll
      for (int bb = 0; bb < 2; ++bb) {
        int b = wg * 2 + bb;
        const float4* pc = (const float4*)(p_ch + (b * 16 + (lane >> 2)) * 20 +
                                           ((lane & 3) << 2));
        float4 pv = pc[0];
        int sb = SADDR(4 * lane);
        const float4* s0 = (const float4*)(s_sl + sb);
        const float4* s1 = (const float4*)(s_sl + sb + 20);
        const float4* s2 = (const float4*)(s_sl + sb + 40);
        const float4* s3 = (const float4*)(s_sl + sb + 60);
        float4 a0 = {0, 0, 0, 0}, a1 = {0, 0, 0, 0}, a2 = {0, 0, 0, 0},
               a3 = {0, 0, 0, 0};
#define FMA4(acc, p, sp)                                              \
        { float4 sv = (sp)[0]; acc.x += (p) * sv.x; acc.y += (p) * sv.y; \
          acc.z += (p) * sv.z; acc.w += (p) * sv.w; }
        FMA4(a0, pv.x, s0); FMA4(a1, pv.x, s0 + 1); FMA4(a2, pv.x, s0 + 2); FMA4(a3, pv.x, s0 + 3);
        FMA4(a0, pv.y, s1); FMA4(a1, pv.y, s1 + 1); FMA4(a2, pv.y, s1 + 2); FMA4(a3, pv.y, s1 + 3);
        FMA4(a0, pv.z, s2); FMA4(a1, pv.z, s2 + 1); FMA4(a2, pv.z, s2 + 2); FMA4(a3, pv.z, s2 + 3);
        FMA4(a0, pv.w, s3); FMA4(a1, pv.w, s3 + 1); FMA4(a2, pv.w, s3 + 2); FMA4(a3, pv.w, s3 + 3);
#undef FMA4
#pragma unroll
        for (int mk = 1; mk <= 32; mk <<= 1) {
          a0.x += __shfl_xor(a0.x, mk); a0.y += __shfl_xor(a0.y, mk);
          a0.z += __shfl_xor(a0.z, mk); a0.w += __shfl_xor(a0.w, mk);
          a1.x += __shfl_xor(a1.x, mk); a1.y += __shfl_xor(a1.y, mk);
          a1.z += __shfl_xor(a1.z, mk); a1.w += __shfl_xor(a1.w, mk);
          a2.x += __shfl_xor(a2.x, mk); a2.y += __shfl_xor(a2.y, mk);
          a2.z += __shfl_xor(a2.z, mk); a2.w += __shfl_xor(a2.w, mk);
          a3.x += __shfl_xor(a3.x, mk); a3.y += __shfl_xor(a3.y, mk);
          a3.z += __shfl_xor(a3.w, mk) - __shfl_xor(a3.w, mk) + __shfl_xor(a3.z, mk);
          a3.w += __shfl_xor(a3.w, mk);
        }
        float* ob = out + (((size_t)(g * GB + b) * S_ + t) << 9) + (cu << 4);
        if (lane == 0) {
          *(float4*)(hp_sl + b * 16 + 0) = a0;  *(float4*)(ob + 0) = a0;
        } else if (lane == 1) {
          *(float4*)(hp_sl + b * 16 + 4) = a1;  *(float4*)(ob + 4) = a1;
        } else if (lane == 2) {
          *(float4*)(hp_sl + b * 16 + 8) = a2;  *(float4*)(ob + 8) = a2;
        } else if (lane == 3) {
          *(float4*)(hp_sl + b * 16 + 12) = a3; *(float4*)(ob + 12) = a3;
        }
      }
    } else if (t + 1 < S_) {
      gemm48(p_ch, gh_sl, wreg, kseg, r48b);
    }
    __syncthreads();
  }

  // final hidden state
  if (tid < 128) {
    int b = tid >> 4, d = tid & 15;
    hn[((size_t)(g * GB + b) << 9) + (cu << 4) + d] = hp_sl[b * 16 + d];
  }
}

// ---------------------------------------------------------------------------
extern "C" void kernel_launch(void* const* d_in, const int* in_sizes, int n_in,
                              void* d_out, int out_size, void* d_ws,
                              size_t ws_size, hipStream_t stream) {
  const float* input = (const float*)d_in[0];
  const float* h0 = (const float*)d_in[1];
  const float* W_ih = (const float*)d_in[2];
  const float* W_hh = (const float*)d_in[3];
  const float* bias_ih = (const float*)d_in[4];
  const float* bias_hh = (const float*)d_in[5];
  const float* states = (const float*)d_in[6];
  float* out = (float*)d_out;

  char* ws = (char*)d_ws;
  unsigned int* flags = (unsigned int*)(ws + WS_FLAGS);
  float* SWT = (float*)(ws + WS_SWT);
  float* Gh0 = (float*)(ws + WS_GH0);
  float* dpart = (float*)(ws + WS_DPART);
  float* dred = (float*)(ws + WS_DRED);

  (void)hipMemsetAsync(d_ws, 0, WS_MEMSET_SZ, stream);  // flags -> 0
  kernel_swt<<<G3H / 8, 256, 0, stream>>>(W_hh, states, SWT);
  kernel_gh0<<<B_, 256, 0, stream>>>(W_hh, h0, Gh0);

  (void)hipFuncSetAttribute(reinterpret_cast<const void*>(srrnn_main),
                            hipFuncAttributeMaxDynamicSharedMemorySize,
                            SMEM_BYTES);
  srrnn_main<<<NG * GC, TPB, SMEM_BYTES, stream>>>(
      input, h0, W_ih, bias_ih, bias_hh, states, SWT, Gh0, dpart, dred, flags,
      out, out + OUT_OFF_HN, out + OUT_OFF_P);
}

// Round 7
// 10208.825 us; speedup vs baseline: 1.0397x; 1.0397x over previous
//
#include <hip/hip_runtime.h>
#include <math.h>

// ---------------------------------------------------------------------------
// SRRNN: state-regularized GRU.  B=64, S=512, I=256, H=512, K=256, TEMP=1.
//
// Round 7 (= R6 design, macro-capture compile fix: DOT4 macro -> dot4 inline).
//  - 32 groups x 8 CUs, 2 batches/group. Each CU owns 64 H-dims (192 gate rows).
//  - SWT slice in registers (24 float4); W_ih streamed from L2 in the barrier
//    shadow (x(t+1) staging + gi(t+1) GEMM overlapped under the flag wait).
//  - ONE barrier per step; partials double-buffered by t&1 (overwrite-safe).
//  - All cross-CU traffic: __hip_atomic_* AGENT (R1/R5-proven). Bounded spins.
// ---------------------------------------------------------------------------

#define B_ 64
#define S_ 512
#define I_ 256
#define H_ 512
#define K_ 256
#define G3H 1536
#define NGRP 32
#define GCU 8
#define NB 2
#define TPB 512
#define SPIN_MAX (1 << 16)

// workspace layout (bytes)
#define WS_FLAGS 0
#define WS_FLAGS_SZ (NGRP * GCU * 4)                   // 1024
#define WS_SWT 4096
#define WS_SWT_SZ (G3H * K_ * 4)                       // 1572864
#define WS_GH0 (WS_SWT + WS_SWT_SZ)
#define WS_GH0_SZ (B_ * G3H * 4)                       // 393216
#define WS_PART (WS_GH0 + WS_GH0_SZ)
#define WS_PART_SZ (2 * NGRP * GCU * NB * K_ * 4)      // 1048576

// LDS float offsets
#define L_SSL 0              // states slice [256][68]
#define L_X 17408            // [2][256]
#define L_P 17920            // [2][256]
#define L_GI 18432           // [2][192]
#define L_GH 18816           // [2][192]
#define L_HC 19200           // [2][64]
#define L_HP 19328           // [2][64]
#define L_BIH 19456          // [192]
#define L_BHH 19648          // [192]
#define L_D 19840            // [2][256]
#define SMEM_BYTES 81920

#define OUT_OFF_HN (B_ * S_ * H_)
#define OUT_OFF_P (OUT_OFF_HN + B_ * H_)

#define AGENT __HIP_MEMORY_SCOPE_AGENT
#define RLX __ATOMIC_RELAXED

// ---------------------------------------------------------------------------
__global__ void kernel_swt(const float* __restrict__ Whh,
                           const float* __restrict__ states,
                           float* __restrict__ SWT) {
  int r0 = blockIdx.x * 8;
  int k = threadIdx.x;  // 0..255
  const float* sr = states + (size_t)k * H_;
  float acc[8];
#pragma unroll
  for (int q = 0; q < 8; ++q) acc[q] = 0.f;
  for (int j = 0; j < H_; ++j) {
    float sv = sr[j];
#pragma unroll
    for (int q = 0; q < 8; ++q) acc[q] += Whh[(size_t)(r0 + q) * H_ + j] * sv;
  }
#pragma unroll
  for (int q = 0; q < 8; ++q) SWT[(size_t)(r0 + q) * K_ + k] = acc[q];
}

__global__ void kernel_gh0(const float* __restrict__ Whh,
                           const float* __restrict__ h0,
                           float* __restrict__ Gh0) {
  int b = blockIdx.x;
  int tid = threadIdx.x;  // 256
  __shared__ float h[H_];
  for (int e = tid; e < H_; e += 256) h[e] = h0[(size_t)b * H_ + e];
  __syncthreads();
  for (int r = tid; r < G3H; r += 256) {
    const float* wr = Whh + (size_t)r * H_;
    float acc = 0.f;
    for (int j = 0; j < H_; ++j) acc += wr[j] * h[j];
    Gh0[(size_t)b * G3H + r] = acc;
  }
}

// ---------------------------------------------------------------------------
__device__ __forceinline__ float dot4(float4 a, float4 b) {
  return a.x * b.x + a.y * b.y + a.z * b.z + a.w * b.w;
}

__global__ __launch_bounds__(TPB, 2) void srrnn_main(
    const float* __restrict__ input, const float* __restrict__ h0,
    const float* __restrict__ W_ih, const float* __restrict__ bias_ih,
    const float* __restrict__ bias_hh, const float* __restrict__ states,
    const float* __restrict__ SWT, const float* __restrict__ Gh0,
    float* __restrict__ part, unsigned int* flags,
    float* __restrict__ out, float* __restrict__ hn,
    float* __restrict__ probs) {
  const int tid = threadIdx.x;
  const int g = blockIdx.x >> 3;   // group 0..31
  const int cu = blockIdx.x & 7;   // CU in group
  const int d0 = cu << 6;          // owned dim base
  unsigned* fl = flags + (g << 3);

  extern __shared__ float smem[];
  float* s_sl = smem + L_SSL;   // [k][j] stride 68
  float* x_sl = smem + L_X;
  float* p_sl = smem + L_P;
  float* gi_sl = smem + L_GI;
  float* gh_sl = smem + L_GH;
  float* hc_sl = smem + L_HC;
  float* hp_sl = smem + L_HP;
  float* bih_sl = smem + L_BIH;
  float* bhh_sl = smem + L_BHH;
  float* d_sl = smem + L_D;

  const int wv = tid >> 6, lane = tid & 63;
  const int rowblk = tid >> 4, kseg = tid & 15;  // gemm org: 32 x 16

  // ---- setup ----
  for (int e = tid; e < K_ * 64; e += TPB) {
    int k = e >> 6, j = e & 63;
    s_sl[k * 68 + j] = states[((size_t)k << 9) + d0 + j];
  }
  if (tid < 192) {
    int grow = ((tid >> 6) << 9) + d0 + (tid & 63);
    bih_sl[tid] = bias_ih[grow];
    bhh_sl[tid] = bias_hh[grow];
  }
  if (tid < 128) {
    int b = tid >> 6, j = tid & 63;
    hp_sl[(b << 6) + j] = h0[((size_t)(g * NB + b) << 9) + d0 + j];
  }
  if (tid < 384) {
    int b = tid / 192, r = tid % 192;
    int grow = ((r >> 6) << 9) + d0 + (r & 63);
    gh_sl[b * 192 + r] = Gh0[(size_t)(g * NB + b) * G3H + grow];
  }
  // SWT fragment -> registers: 6 rows x 16 k per thread
  float4 wh[6][4];
#pragma unroll
  for (int i = 0; i < 6; ++i) {
    int r = rowblk * 6 + i;
    int grow = ((r >> 6) << 9) + d0 + (r & 63);
    const float4* src = (const float4*)(SWT + (size_t)grow * K_ + (kseg << 4));
    wh[i][0] = src[0]; wh[i][1] = src[1]; wh[i][2] = src[2]; wh[i][3] = src[3];
  }
  __syncthreads();

  // ---- pre-loop: stage x(0), gi(0) ----
  if (tid < 128) {
    int b = tid >> 6, q = tid & 63;
    float4 v = *((const float4*)(input + ((size_t)(g * NB + b) * S_) * I_) + q);
    *(float4*)(x_sl + (b << 8) + (q << 2)) = v;
  }
  __syncthreads();
  {
    float4 xa[2][4];
#pragma unroll
    for (int b = 0; b < 2; ++b) {
      const float4* xp = (const float4*)(x_sl + (b << 8) + (kseg << 4));
      xa[b][0] = xp[0]; xa[b][1] = xp[1]; xa[b][2] = xp[2]; xa[b][3] = xp[3];
    }
    float acc[2][6] = {};
#pragma unroll
    for (int c = 0; c < 4; ++c) {
#pragma unroll
      for (int i = 0; i < 6; ++i) {
        int r = rowblk * 6 + i;
        int grow = ((r >> 6) << 9) + d0 + (r & 63);
        float4 w = *(const float4*)(W_ih + (size_t)grow * K_ + (kseg << 4) + (c << 2));
        acc[0][i] += dot4(w, xa[0][c]);
        acc[1][i] += dot4(w, xa[1][c]);
      }
    }
#pragma unroll
    for (int b = 0; b < 2; ++b)
#pragma unroll
      for (int i = 0; i < 6; ++i) {
        float v = acc[b][i];
        v += __shfl_xor(v, 1); v += __shfl_xor(v, 2);
        v += __shfl_xor(v, 4); v += __shfl_xor(v, 8);
        acc[b][i] = v;
      }
    if (kseg == 0) {
#pragma unroll
      for (int b = 0; b < 2; ++b)
#pragma unroll
        for (int i = 0; i < 6; ++i) gi_sl[b * 192 + rowblk * 6 + i] = acc[b][i];
    }
  }
  __syncthreads();

  for (int t = 0; t < S_; ++t) {
    const int slot = t & 1;
    float* pslot = part + ((size_t)(slot * NGRP + g) << 12);  // [8][2][256]

    // ---- A: gates + h_cand over owned 64 dims ----
    if (tid < 128) {
      int b = tid >> 6, j = tid & 63;
      float gir = gi_sl[b * 192 + j] + bih_sl[j];
      float giz = gi_sl[b * 192 + 64 + j] + bih_sl[64 + j];
      float gin = gi_sl[b * 192 + 128 + j] + bih_sl[128 + j];
      float ghr = gh_sl[b * 192 + j] + bhh_sl[j];
      float ghz = gh_sl[b * 192 + 64 + j] + bhh_sl[64 + j];
      float ghn = gh_sl[b * 192 + 128 + j] + bhh_sl[128 + j];
      float r = 1.f / (1.f + expf(-(gir + ghr)));
      float z = 1.f / (1.f + expf(-(giz + ghz)));
      float n = tanhf(gin + r * ghn);
      hc_sl[(b << 6) + j] = (1.f - z) * n + z * hp_sl[(b << 6) + j];
    }
    __syncthreads();

    // ---- B: dist partial over own 64 dims, thread = (b, k) ----
    {
      int b = tid >> 8, k = tid & 255;
      const float4* sr = (const float4*)(s_sl + k * 68);
      const float4* hr = (const float4*)(hc_sl + (b << 6));
      float a = 0.f;
#pragma unroll
      for (int i = 0; i < 16; ++i) {
        float4 s4 = sr[i], h4 = hr[i];
        float e;
        e = h4.x - s4.x; a += e * e;
        e = h4.y - s4.y; a += e * e;
        e = h4.z - s4.z; a += e * e;
        e = h4.w - s4.w; a += e * e;
      }
      __hip_atomic_store(pslot + (cu << 9) + (b << 8) + k, a, RLX, AGENT);
    }
    __syncthreads();  // drains vmcnt before release
    if (tid == 0)
      __hip_atomic_store(fl + cu, (unsigned)(t + 1), __ATOMIC_RELEASE, AGENT);

    // ---- C (barrier shadow): stage x(t+1) + gi(t+1) GEMM (W_ih from L2) ----
    if (t + 1 < S_) {
      if (tid < 128) {
        int b = tid >> 6, q = tid & 63;
        float4 v = *((const float4*)(input +
                     ((size_t)(g * NB + b) * S_ + (t + 1)) * I_) + q);
        *(float4*)(x_sl + (b << 8) + (q << 2)) = v;
      }
      __syncthreads();
      {
        float4 xa[2][4];
#pragma unroll
        for (int b = 0; b < 2; ++b) {
          const float4* xp = (const float4*)(x_sl + (b << 8) + (kseg << 4));
          xa[b][0] = xp[0]; xa[b][1] = xp[1]; xa[b][2] = xp[2]; xa[b][3] = xp[3];
        }
        float acc[2][6] = {};
#pragma unroll
        for (int c = 0; c < 4; ++c) {
#pragma unroll
          for (int i = 0; i < 6; ++i) {
            int r = rowblk * 6 + i;
            int grow = ((r >> 6) << 9) + d0 + (r & 63);
            float4 w = *(const float4*)(W_ih + (size_t)grow * K_ +
                                        (kseg << 4) + (c << 2));
            acc[0][i] += dot4(w, xa[0][c]);
            acc[1][i] += dot4(w, xa[1][c]);
          }
        }
#pragma unroll
        for (int b = 0; b < 2; ++b)
#pragma unroll
          for (int i = 0; i < 6; ++i) {
            float v = acc[b][i];
            v += __shfl_xor(v, 1); v += __shfl_xor(v, 2);
            v += __shfl_xor(v, 4); v += __shfl_xor(v, 8);
            acc[b][i] = v;
          }
        if (kseg == 0) {
#pragma unroll
          for (int b = 0; b < 2; ++b)
#pragma unroll
            for (int i = 0; i < 6; ++i)
              gi_sl[b * 192 + rowblk * 6 + i] = acc[b][i];
        }
      }
    }

    // ---- E: poll the 8 flags ----
    if (tid < GCU) {
      for (int it = 0; it < SPIN_MAX; ++it) {
        if (__hip_atomic_load(fl + tid, RLX, AGENT) >= (unsigned)(t + 1)) break;
        __builtin_amdgcn_s_sleep(1);
      }
    }
    __syncthreads();

    // ---- F: gather 8 partials (coalesced), sum -> d_sl ----
    {
      int b = tid >> 8, k = tid & 255;
      const float* q = pslot + (b << 8) + k;  // cu stride = 512 floats
      float s = 0.f;
#pragma unroll
      for (int c = 0; c < GCU; ++c)
        s += __hip_atomic_load(q + (c << 9), RLX, AGENT);
      d_sl[(b << 8) + k] = s;
    }
    __syncthreads();

    // ---- G: softmax (waves 0-1), p + probs ----
    if (wv < 2) {
      int b = wv;
      const float* db = d_sl + (b << 8);
      float dd0 = db[lane], dd1 = db[lane + 64], dd2 = db[lane + 128],
            dd3 = db[lane + 192];
      float mn = fminf(fminf(dd0, dd1), fminf(dd2, dd3));
#pragma unroll
      for (int off = 32; off >= 1; off >>= 1) mn = fminf(mn, __shfl_xor(mn, off));
      float e0 = expf(mn - dd0), e1 = expf(mn - dd1), e2 = expf(mn - dd2),
            e3 = expf(mn - dd3);
      float s = (e0 + e1) + (e2 + e3);
#pragma unroll
      for (int off = 32; off >= 1; off >>= 1) s += __shfl_xor(s, off);
      float inv = 1.f / s;
      e0 *= inv; e1 *= inv; e2 *= inv; e3 *= inv;
      float* pb = p_sl + (b << 8);
      pb[lane] = e0; pb[lane + 64] = e1; pb[lane + 128] = e2; pb[lane + 192] = e3;
      if (cu == 0) {
        float* pr = probs + (((size_t)(g * NB + b) * S_ + t) << 8);
        pr[lane] = e0; pr[lane + 64] = e1; pr[lane + 128] = e2; pr[lane + 192] = e3;
      }
    }
    __syncthreads();

    // ---- H1: gh(t+1) GEMM from registers (SWT) ----
    if (t + 1 < S_) {
      float4 xa[2][4];
#pragma unroll
      for (int b = 0; b < 2; ++b) {
        const float4* xp = (const float4*)(p_sl + (b << 8) + (kseg << 4));
        xa[b][0] = xp[0]; xa[b][1] = xp[1]; xa[b][2] = xp[2]; xa[b][3] = xp[3];
      }
      float acc[2][6] = {};
#pragma unroll
      for (int c = 0; c < 4; ++c) {
#pragma unroll
        for (int i = 0; i < 6; ++i) {
          acc[0][i] += dot4(wh[i][c], xa[0][c]);
          acc[1][i] += dot4(wh[i][c], xa[1][c]);
        }
      }
#pragma unroll
      for (int b = 0; b < 2; ++b)
#pragma unroll
        for (int i = 0; i < 6; ++i) {
          float v = acc[b][i];
          v += __shfl_xor(v, 1); v += __shfl_xor(v, 2);
          v += __shfl_xor(v, 4); v += __shfl_xor(v, 8);
          acc[b][i] = v;
        }
      if (kseg == 0) {
#pragma unroll
        for (int b = 0; b < 2; ++b)
#pragma unroll
          for (int i = 0; i < 6; ++i)
            gh_sl[b * 192 + rowblk * 6 + i] = acc[b][i];
      }
    }

    // ---- H2: h_new over own dims. thread = (b, j4, kq): k = kq + 16i ----
    {
      int b = tid >> 8;
      int j4 = (tid >> 4) & 15;     // output float4 index (j = 4*j4..4*j4+3)
      int kq = tid & 15;
      const float* pb = p_sl + (b << 8);
      float4 a = {0.f, 0.f, 0.f, 0.f};
#pragma unroll
      for (int i = 0; i < 16; ++i) {
        int k = kq + (i << 4);
        float pv = pb[k];
        float4 sv = *(const float4*)(s_sl + k * 68 + (j4 << 2));
        a.x += pv * sv.x; a.y += pv * sv.y; a.z += pv * sv.z; a.w += pv * sv.w;
      }
#pragma unroll
      for (int off = 8; off >= 1; off >>= 1) {
        a.x += __shfl_xor(a.x, off); a.y += __shfl_xor(a.y, off);
        a.z += __shfl_xor(a.z, off); a.w += __shfl_xor(a.w, off);
      }
      if (kq == 0) {
        *(float4*)(hp_sl + (b << 6) + (j4 << 2)) = a;
        float* ob = out + (((size_t)(g * NB + b) * S_ + t) << 9) + d0 + (j4 << 2);
        *(float4*)ob = a;
      }
    }
    __syncthreads();
  }

  // ---- final hidden state ----
  if (tid < 128) {
    int b = tid >> 6, j = tid & 63;
    hn[((size_t)(g * NB + b) << 9) + d0 + j] = hp_sl[(b << 6) + j];
  }
}

// ---------------------------------------------------------------------------
extern "C" void kernel_launch(void* const* d_in, const int* in_sizes, int n_in,
                              void* d_out, int out_size, void* d_ws,
                              size_t ws_size, hipStream_t stream) {
  const float* input = (const float*)d_in[0];
  const float* h0 = (const float*)d_in[1];
  const float* W_ih = (const float*)d_in[2];
  const float* W_hh = (const float*)d_in[3];
  const float* bias_ih = (const float*)d_in[4];
  const float* bias_hh = (const float*)d_in[5];
  const float* states = (const float*)d_in[6];
  float* out = (float*)d_out;

  char* ws = (char*)d_ws;
  unsigned int* flags = (unsigned int*)(ws + WS_FLAGS);
  float* SWT = (float*)(ws + WS_SWT);
  float* Gh0 = (float*)(ws + WS_GH0);
  float* part = (float*)(ws + WS_PART);

  (void)hipMemsetAsync(d_ws, 0, WS_FLAGS_SZ, stream);  // flags -> 0
  kernel_swt<<<G3H / 8, 256, 0, stream>>>(W_hh, states, SWT);
  kernel_gh0<<<B_, 256, 0, stream>>>(W_hh, h0, Gh0);

  (void)hipFuncSetAttribute(reinterpret_cast<const void*>(srrnn_main),
                            hipFuncAttributeMaxDynamicSharedMemorySize,
                            SMEM_BYTES);
  srrnn_main<<<NGRP * GCU, TPB, SMEM_BYTES, stream>>>(
      input, h0, W_ih, bias_ih, bias_hh, states, SWT, Gh0, part, flags,
      out, out + OUT_OFF_HN, out + OUT_OFF_P);
}

// Round 8
// 9717.715 us; speedup vs baseline: 1.0922x; 1.0505x over previous
//
#include <hip/hip_runtime.h>
#include <math.h>

// ---------------------------------------------------------------------------
// SRRNN: state-regularized GRU.  B=64, S=512, I=256, H=512, K=256, TEMP=1.
//
// Round 8: R7 sync structure (1 barrier/step, 8-CU groups, agent-scope
// scalar atomics) + three data-path fixes:
//  - BOTH weight slices in registers: wi[6][4] (W_ih) + wh[6][4] (SWT) per
//    thread = 192 VGPR. No per-step weight memory traffic at all (R7 fetched
//    11.3 GB of W_ih from HBM due to cross-XCD L2 thrash).
//  - Transposed states s_T[64][260]: dist reads are lane-consecutive float4
//    (conflict-free); h_new spreads bank-groups via strided k-chunks.
//  - p in chunked [2][16][20] layout (R5-proven) for conflict-free gh reads.
// ---------------------------------------------------------------------------

#define B_ 64
#define S_ 512
#define I_ 256
#define H_ 512
#define K_ 256
#define G3H 1536
#define NGRP 32
#define GCU 8
#define NB 2
#define TPB 512
#define SPIN_MAX (1 << 14)

// workspace layout (bytes)
#define WS_FLAGS 0
#define WS_FLAGS_SZ (NGRP * GCU * 4)                   // 1024
#define WS_SWT 4096
#define WS_SWT_SZ (G3H * K_ * 4)
#define WS_GH0 (WS_SWT + WS_SWT_SZ)
#define WS_GH0_SZ (B_ * G3H * 4)
#define WS_PART (WS_GH0 + WS_GH0_SZ)
#define WS_PART_SZ (2 * NGRP * GCU * NB * K_ * 4)      // 1048576

// LDS float offsets
#define L_ST 0               // s_T[64][260]  (transposed states, j-major)
#define L_X 16640            // x_sl [2][256]
#define L_PCH 17152          // p_ch [2][16][20]
#define L_GI 17792           // gi_sl [2][192]
#define L_GH 18176           // gh_sl [2][192]
#define L_HC 18560           // hc_sl [2][64]
#define L_HP 18688           // hp_sl [2][64]
#define L_BIH 18816          // [192]
#define L_BHH 19008          // [192]
#define L_D 19200            // d_sl [2][256]
#define SMEM_BYTES 86016     // 84KB: forces 1 block/CU

#define OUT_OFF_HN (B_ * S_ * H_)
#define OUT_OFF_P (OUT_OFF_HN + B_ * H_)

#define AGENT __HIP_MEMORY_SCOPE_AGENT
#define RLX __ATOMIC_RELAXED

// ---------------------------------------------------------------------------
__global__ void kernel_swt(const float* __restrict__ Whh,
                           const float* __restrict__ states,
                           float* __restrict__ SWT) {
  int r0 = blockIdx.x * 8;
  int k = threadIdx.x;  // 0..255
  const float* sr = states + (size_t)k * H_;
  float acc[8];
#pragma unroll
  for (int q = 0; q < 8; ++q) acc[q] = 0.f;
  for (int j = 0; j < H_; ++j) {
    float sv = sr[j];
#pragma unroll
    for (int q = 0; q < 8; ++q) acc[q] += Whh[(size_t)(r0 + q) * H_ + j] * sv;
  }
#pragma unroll
  for (int q = 0; q < 8; ++q) SWT[(size_t)(r0 + q) * K_ + k] = acc[q];
}

__global__ void kernel_gh0(const float* __restrict__ Whh,
                           const float* __restrict__ h0,
                           float* __restrict__ Gh0) {
  int b = blockIdx.x;
  int tid = threadIdx.x;  // 256
  __shared__ float h[H_];
  for (int e = tid; e < H_; e += 256) h[e] = h0[(size_t)b * H_ + e];
  __syncthreads();
  for (int r = tid; r < G3H; r += 256) {
    const float* wr = Whh + (size_t)r * H_;
    float acc = 0.f;
    for (int j = 0; j < H_; ++j) acc += wr[j] * h[j];
    Gh0[(size_t)b * G3H + r] = acc;
  }
}

// ---------------------------------------------------------------------------
__device__ __forceinline__ float dot4(float4 a, float4 b) {
  return a.x * b.x + a.y * b.y + a.z * b.z + a.w * b.w;
}

__global__ __launch_bounds__(TPB) void srrnn_main(
    const float* __restrict__ input, const float* __restrict__ h0,
    const float* __restrict__ W_ih, const float* __restrict__ bias_ih,
    const float* __restrict__ bias_hh, const float* __restrict__ states,
    const float* __restrict__ SWT, const float* __restrict__ Gh0,
    float* __restrict__ part, unsigned int* flags,
    float* __restrict__ out, float* __restrict__ hn,
    float* __restrict__ probs) {
  const int tid = threadIdx.x;
  const int g = blockIdx.x >> 3;   // group 0..31
  const int cu = blockIdx.x & 7;   // CU in group
  const int d0 = cu << 6;          // owned dim base (64 dims)
  unsigned* fl = flags + (g << 3);

  extern __shared__ float smem[];
  float* s_T = smem + L_ST;        // [j][260]
  float* x_sl = smem + L_X;
  float* p_ch = smem + L_PCH;      // [2][16][20]
  float* gi_sl = smem + L_GI;
  float* gh_sl = smem + L_GH;
  float* hc_sl = smem + L_HC;
  float* hp_sl = smem + L_HP;
  float* bih_sl = smem + L_BIH;
  float* bhh_sl = smem + L_BHH;
  float* d_sl = smem + L_D;

  const int wv = tid >> 6, lane = tid & 63;
  const int rowblk = tid >> 4, kseg = tid & 15;  // GEMM org: 32 x 16

  // ---- setup ----
  // transposed states: s_T[j][k], coalesced global reads (j inner)
  for (int e = tid; e < K_ * 64; e += TPB) {
    int k = e >> 6, j = e & 63;
    s_T[j * 260 + k] = states[((size_t)k << 9) + d0 + j];
  }
  if (tid < 192) {
    int grow = ((tid >> 6) << 9) + d0 + (tid & 63);
    bih_sl[tid] = bias_ih[grow];
    bhh_sl[tid] = bias_hh[grow];
  }
  if (tid < 128) {
    int b = tid >> 6, j = tid & 63;
    hp_sl[(b << 6) + j] = h0[((size_t)(g * NB + b) << 9) + d0 + j];
  }
  if (tid < 384) {
    int b = tid / 192, r = tid % 192;
    int grow = ((r >> 6) << 9) + d0 + (r & 63);
    gh_sl[b * 192 + r] = Gh0[(size_t)(g * NB + b) * G3H + grow];
  }
  // weight fragments -> registers: 6 rows x 16 k per thread, both matrices
  float4 wi[6][4], wh[6][4];
#pragma unroll
  for (int i = 0; i < 6; ++i) {
    int r = rowblk * 6 + i;
    int grow = ((r >> 6) << 9) + d0 + (r & 63);
    const float4* si = (const float4*)(W_ih + (size_t)grow * K_ + (kseg << 4));
    const float4* sh = (const float4*)(SWT + (size_t)grow * K_ + (kseg << 4));
    wi[i][0] = si[0]; wi[i][1] = si[1]; wi[i][2] = si[2]; wi[i][3] = si[3];
    wh[i][0] = sh[0]; wh[i][1] = sh[1]; wh[i][2] = sh[2]; wh[i][3] = sh[3];
  }
  __syncthreads();

  // ---- pre-loop: stage x(0), gi(0) ----
  if (tid < 128) {
    int b = tid >> 6, q = tid & 63;
    float4 v = *((const float4*)(input + ((size_t)(g * NB + b) * S_) * I_) + q);
    *(float4*)(x_sl + (b << 8) + (q << 2)) = v;
  }
  __syncthreads();
  {
    float acc[2][6] = {};
#pragma unroll
    for (int b = 0; b < 2; ++b) {
      const float4* xp = (const float4*)(x_sl + (b << 8) + (kseg << 4));
#pragma unroll
      for (int c = 0; c < 4; ++c) {
        float4 xv = xp[c];
#pragma unroll
        for (int i = 0; i < 6; ++i) acc[b][i] += dot4(wi[i][c], xv);
      }
    }
#pragma unroll
    for (int b = 0; b < 2; ++b)
#pragma unroll
      for (int i = 0; i < 6; ++i) {
        float v = acc[b][i];
        v += __shfl_xor(v, 1); v += __shfl_xor(v, 2);
        v += __shfl_xor(v, 4); v += __shfl_xor(v, 8);
        acc[b][i] = v;
      }
    if (kseg == 0) {
#pragma unroll
      for (int b = 0; b < 2; ++b)
#pragma unroll
        for (int i = 0; i < 6; ++i) gi_sl[b * 192 + rowblk * 6 + i] = acc[b][i];
    }
  }
  __syncthreads();

  for (int t = 0; t < S_; ++t) {
    const int slot = t & 1;
    float* pslot = part + ((size_t)(slot * NGRP + g) << 12);  // [8][2][256]

    // ---- A: gates + h_cand over owned 64 dims ----
    if (tid < 128) {
      int b = tid >> 6, j = tid & 63;
      float gir = gi_sl[b * 192 + j] + bih_sl[j];
      float giz = gi_sl[b * 192 + 64 + j] + bih_sl[64 + j];
      float gin = gi_sl[b * 192 + 128 + j] + bih_sl[128 + j];
      float ghr = gh_sl[b * 192 + j] + bhh_sl[j];
      float ghz = gh_sl[b * 192 + 64 + j] + bhh_sl[64 + j];
      float ghn = gh_sl[b * 192 + 128 + j] + bhh_sl[128 + j];
      float r = 1.f / (1.f + expf(-(gir + ghr)));
      float z = 1.f / (1.f + expf(-(giz + ghz)));
      float n = tanhf(gin + r * ghn);
      hc_sl[(b << 6) + j] = (1.f - z) * n + z * hp_sl[(b << 6) + j];
    }
    __syncthreads();

    // ---- B: dist partial. thread = (b, k4, jq); k = 4*k4.., j = 16*jq.. ----
    {
      int b = tid >> 8, k4 = (tid >> 2) & 63, jq = tid & 3;
      float ax = 0.f, ay = 0.f, az = 0.f, aw = 0.f;
      const float* sb = s_T + (jq << 4) * 260 + (k4 << 2);
      const float* hb = hc_sl + (b << 6) + (jq << 4);
#pragma unroll
      for (int i = 0; i < 16; ++i) {
        float4 s4 = *(const float4*)(sb + i * 260);
        float hv = hb[i];
        float e;
        e = hv - s4.x; ax += e * e;
        e = hv - s4.y; ay += e * e;
        e = hv - s4.z; az += e * e;
        e = hv - s4.w; aw += e * e;
      }
      ax += __shfl_xor(ax, 1); ax += __shfl_xor(ax, 2);
      ay += __shfl_xor(ay, 1); ay += __shfl_xor(ay, 2);
      az += __shfl_xor(az, 1); az += __shfl_xor(az, 2);
      aw += __shfl_xor(aw, 1); aw += __shfl_xor(aw, 2);
      if (jq == 0) {
        float* dpb = pslot + (cu << 9) + (b << 8) + (k4 << 2);
        __hip_atomic_store(dpb + 0, ax, RLX, AGENT);
        __hip_atomic_store(dpb + 1, ay, RLX, AGENT);
        __hip_atomic_store(dpb + 2, az, RLX, AGENT);
        __hip_atomic_store(dpb + 3, aw, RLX, AGENT);
      }
    }
    __syncthreads();  // per-wave vmcnt drained before barrier -> stores done
    if (tid == 0)
      __hip_atomic_store(fl + cu, (unsigned)(t + 1), __ATOMIC_RELEASE, AGENT);

    // ---- C (barrier shadow): stage x(t+1), gi(t+1) GEMM (register W_ih) ----
    if (t + 1 < S_) {
      if (tid < 128) {
        int b = tid >> 6, q = tid & 63;
        float4 v = *((const float4*)(input +
                     ((size_t)(g * NB + b) * S_ + (t + 1)) * I_) + q);
        *(float4*)(x_sl + (b << 8) + (q << 2)) = v;
      }
      __syncthreads();
      {
        float acc[2][6] = {};
#pragma unroll
        for (int b = 0; b < 2; ++b) {
          const float4* xp = (const float4*)(x_sl + (b << 8) + (kseg << 4));
#pragma unroll
          for (int c = 0; c < 4; ++c) {
            float4 xv = xp[c];
#pragma unroll
            for (int i = 0; i < 6; ++i) acc[b][i] += dot4(wi[i][c], xv);
          }
        }
#pragma unroll
        for (int b = 0; b < 2; ++b)
#pragma unroll
          for (int i = 0; i < 6; ++i) {
            float v = acc[b][i];
            v += __shfl_xor(v, 1); v += __shfl_xor(v, 2);
            v += __shfl_xor(v, 4); v += __shfl_xor(v, 8);
            acc[b][i] = v;
          }
        if (kseg == 0) {
#pragma unroll
          for (int b = 0; b < 2; ++b)
#pragma unroll
            for (int i = 0; i < 6; ++i)
              gi_sl[b * 192 + rowblk * 6 + i] = acc[b][i];
        }
      }
    }

    // ---- E: poll the 8 flags ----
    if (tid < GCU) {
      for (int it = 0; it < SPIN_MAX; ++it) {
        if (__hip_atomic_load(fl + tid, RLX, AGENT) >= (unsigned)(t + 1)) break;
        __builtin_amdgcn_s_sleep(1);
      }
    }
    __syncthreads();

    // ---- F: gather 8 partials (coalesced), sum -> d_sl ----
    {
      int b = tid >> 8, k = tid & 255;
      const float* q = pslot + (b << 8) + k;  // cu stride = 512 floats
      float s = 0.f;
#pragma unroll
      for (int c = 0; c < GCU; ++c)
        s += __hip_atomic_load(q + (c << 9), RLX, AGENT);
      d_sl[(b << 8) + k] = s;
    }
    __syncthreads();

    // ---- G: softmax (waves 0-1) -> p_ch chunked + probs ----
    if (wv < 2) {
      int b = wv;
      const float* db = d_sl + (b << 8);
      float dd0 = db[lane], dd1 = db[lane + 64], dd2 = db[lane + 128],
            dd3 = db[lane + 192];
      float mn = fminf(fminf(dd0, dd1), fminf(dd2, dd3));
#pragma unroll
      for (int off = 32; off >= 1; off >>= 1) mn = fminf(mn, __shfl_xor(mn, off));
      float e0 = expf(mn - dd0), e1 = expf(mn - dd1), e2 = expf(mn - dd2),
            e3 = expf(mn - dd3);
      float s = (e0 + e1) + (e2 + e3);
#pragma unroll
      for (int off = 32; off >= 1; off >>= 1) s += __shfl_xor(s, off);
      float inv = 1.f / s;
      e0 *= inv; e1 *= inv; e2 *= inv; e3 *= inv;
      // k -> (chunk = k>>4, pos = k&15), addr = (b*16+chunk)*20 + pos
      int hi = lane >> 4, lo = lane & 15;
      p_ch[(b * 16 + hi + 0) * 20 + lo] = e0;
      p_ch[(b * 16 + hi + 4) * 20 + lo] = e1;
      p_ch[(b * 16 + hi + 8) * 20 + lo] = e2;
      p_ch[(b * 16 + hi + 12) * 20 + lo] = e3;
      if (cu == 0) {
        float* pr = probs + (((size_t)(g * NB + b) * S_ + t) << 8);
        pr[lane] = e0; pr[lane + 64] = e1; pr[lane + 128] = e2; pr[lane + 192] = e3;
      }
    }
    __syncthreads();

    // ---- H1: gh(t+1) GEMM from registers (SWT); p from chunked layout ----
    if (t + 1 < S_) {
      float acc[2][6] = {};
#pragma unroll
      for (int b = 0; b < 2; ++b) {
        const float4* xp = (const float4*)(p_ch + (b * 16 + kseg) * 20);
#pragma unroll
        for (int c = 0; c < 4; ++c) {
          float4 xv = xp[c];
#pragma unroll
          for (int i = 0; i < 6; ++i) acc[b][i] += dot4(wh[i][c], xv);
        }
      }
#pragma unroll
      for (int b = 0; b < 2; ++b)
#pragma unroll
        for (int i = 0; i < 6; ++i) {
          float v = acc[b][i];
          v += __shfl_xor(v, 1); v += __shfl_xor(v, 2);
          v += __shfl_xor(v, 4); v += __shfl_xor(v, 8);
          acc[b][i] = v;
        }
      if (kseg == 0) {
#pragma unroll
        for (int b = 0; b < 2; ++b)
#pragma unroll
          for (int i = 0; i < 6; ++i)
            gh_sl[b * 192 + rowblk * 6 + i] = acc[b][i];
      }
    }

    // ---- H2: h_new over own dims. thread = (b, j, kq); k-chunks c=kq+4i ----
    {
      int b = tid >> 8, j = (tid >> 2) & 63, kq = tid & 3;
      float a = 0.f;
#pragma unroll
      for (int i = 0; i < 16; ++i) {
        int c = kq + (i << 2);  // float4-of-k index 0..63
        float4 p4 = *(const float4*)(p_ch + (b * 16 + (c >> 2)) * 20 +
                                     ((c & 3) << 2));
        float4 s4 = *(const float4*)(s_T + j * 260 + (c << 2));
        a += dot4(p4, s4);
      }
      a += __shfl_xor(a, 1);
      a += __shfl_xor(a, 2);
      if (kq == 0) {
        hp_sl[(b << 6) + j] = a;
        out[(((size_t)(g * NB + b) * S_ + t) << 9) + d0 + j] = a;
      }
    }
    __syncthreads();
  }

  // ---- final hidden state ----
  if (tid < 128) {
    int b = tid >> 6, j = tid & 63;
    hn[((size_t)(g * NB + b) << 9) + d0 + j] = hp_sl[(b << 6) + j];
  }
}

// ---------------------------------------------------------------------------
extern "C" void kernel_launch(void* const* d_in, const int* in_sizes, int n_in,
                              void* d_out, int out_size, void* d_ws,
                              size_t ws_size, hipStream_t stream) {
  const float* input = (const float*)d_in[0];
  const float* h0 = (const float*)d_in[1];
  const float* W_ih = (const float*)d_in[2];
  const float* W_hh = (const float*)d_in[3];
  const float* bias_ih = (const float*)d_in[4];
  const float* bias_hh = (const float*)d_in[5];
  const float* states = (const float*)d_in[6];
  float* out = (float*)d_out;

  char* ws = (char*)d_ws;
  unsigned int* flags = (unsigned int*)(ws + WS_FLAGS);
  float* SWT = (float*)(ws + WS_SWT);
  float* Gh0 = (float*)(ws + WS_GH0);
  float* part = (float*)(ws + WS_PART);

  (void)hipMemsetAsync(d_ws, 0, WS_FLAGS_SZ, stream);  // flags -> 0
  kernel_swt<<<G3H / 8, 256, 0, stream>>>(W_hh, states, SWT);
  kernel_gh0<<<B_, 256, 0, stream>>>(W_hh, h0, Gh0);

  (void)hipFuncSetAttribute(reinterpret_cast<const void*>(srrnn_main),
                            hipFuncAttributeMaxDynamicSharedMemorySize,
                            SMEM_BYTES);
  srrnn_main<<<NGRP * GCU, TPB, SMEM_BYTES, stream>>>(
      input, h0, W_ih, bias_ih, bias_hh, states, SWT, Gh0, part, flags,
      out, out + OUT_OFF_HN, out + OUT_OFF_P);
}

// Round 9
// 5933.374 us; speedup vs baseline: 1.7888x; 1.6378x over previous
//
#include <hip/hip_runtime.h>
#include <math.h>

// ---------------------------------------------------------------------------
// SRRNN: state-regularized GRU.  B=64, S=512, I=256, H=512, K=256, TEMP=1.
//
// Round 9: weight slices sized to the PROVEN register budget.
//  - 16 groups x 16 CUs, NB=4 batches/group, 32 dims/CU (96 gate rows).
//    Per-thread weights: 3 rows x 16 k x 2 matrices = 24 float4 = 96 VGPRs
//    (R5/R7-proven resident; R8's 48 float4 was refused -> 10.7GB refetch).
//  - One barrier/step (16 flags), agent-scope scalar atomics (R5-proven),
//    partials double-buffered by t&1.
//  - Two LDS states copies with conflict-matched layouts:
//      s_T[32][256]  -> dist: scalar loop over j, lane=k  (conflict-free)
//      s_sl[256][36] -> h_new: scalar loop over k, lane=j (conflict-free)
//  - gi(t+1) GEMM + x(t+1) staging in the barrier shadow.
// ---------------------------------------------------------------------------

#define B_ 64
#define S_ 512
#define I_ 256
#define H_ 512
#define K_ 256
#define G3H 1536
#define NGRP 16
#define GCU 16
#define NB 4
#define DPC 32     // dims per CU
#define TPB 512
#define SPIN_MAX (1 << 14)

// workspace layout (bytes)
#define WS_FLAGS 0
#define WS_FLAGS_SZ (NGRP * GCU * 4)                   // 1024
#define WS_SWT 4096
#define WS_SWT_SZ (G3H * K_ * 4)
#define WS_GH0 (WS_SWT + WS_SWT_SZ)
#define WS_GH0_SZ (B_ * G3H * 4)
#define WS_PART (WS_GH0 + WS_GH0_SZ)
#define WS_PART_SZ (2 * NGRP * GCU * NB * K_ * 4)      // 2097152

// LDS float offsets
#define L_ST 0               // s_T[32][256]  (j-major rows of owned dims)
#define L_SSL 8192           // s_sl[256][36] (k-major, stride 36)
#define L_X 17408            // x_sl [4][256]
#define L_P 18432            // p_sl [4][256]
#define L_GI 19456           // gi_sl [4][96]
#define L_GH 19840           // gh_sl [4][96]
#define L_HC 20224           // hc_sl [4][32]
#define L_HP 20352           // hp_sl [4][32]
#define L_BIH 20480          // [96]
#define L_BHH 20576          // [96]
#define L_D 20672            // d_sl [4][256]
#define SMEM_BYTES 87040     // 21696 floats = 86784B, padded; >80KB -> 1 blk/CU

#define OUT_OFF_HN (B_ * S_ * H_)
#define OUT_OFF_P (OUT_OFF_HN + B_ * H_)

#define AGENT __HIP_MEMORY_SCOPE_AGENT
#define RLX __ATOMIC_RELAXED

// ---------------------------------------------------------------------------
__global__ void kernel_swt(const float* __restrict__ Whh,
                           const float* __restrict__ states,
                           float* __restrict__ SWT) {
  int r0 = blockIdx.x * 8;
  int k = threadIdx.x;  // 0..255
  const float* sr = states + (size_t)k * H_;
  float acc[8];
#pragma unroll
  for (int q = 0; q < 8; ++q) acc[q] = 0.f;
  for (int j = 0; j < H_; ++j) {
    float sv = sr[j];
#pragma unroll
    for (int q = 0; q < 8; ++q) acc[q] += Whh[(size_t)(r0 + q) * H_ + j] * sv;
  }
#pragma unroll
  for (int q = 0; q < 8; ++q) SWT[(size_t)(r0 + q) * K_ + k] = acc[q];
}

__global__ void kernel_gh0(const float* __restrict__ Whh,
                           const float* __restrict__ h0,
                           float* __restrict__ Gh0) {
  int b = blockIdx.x;
  int tid = threadIdx.x;  // 256
  __shared__ float h[H_];
  for (int e = tid; e < H_; e += 256) h[e] = h0[(size_t)b * H_ + e];
  __syncthreads();
  for (int r = tid; r < G3H; r += 256) {
    const float* wr = Whh + (size_t)r * H_;
    float acc = 0.f;
    for (int j = 0; j < H_; ++j) acc += wr[j] * h[j];
    Gh0[(size_t)b * G3H + r] = acc;
  }
}

// ---------------------------------------------------------------------------
__device__ __forceinline__ float dot4(float4 a, float4 b) {
  return a.x * b.x + a.y * b.y + a.z * b.z + a.w * b.w;
}

__global__ __launch_bounds__(TPB, 2) void srrnn_main(
    const float* __restrict__ input, const float* __restrict__ h0,
    const float* __restrict__ W_ih, const float* __restrict__ bias_ih,
    const float* __restrict__ bias_hh, const float* __restrict__ states,
    const float* __restrict__ SWT, const float* __restrict__ Gh0,
    float* __restrict__ part, unsigned int* flags,
    float* __restrict__ out, float* __restrict__ hn,
    float* __restrict__ probs) {
  const int tid = threadIdx.x;
  const int g = blockIdx.x >> 4;   // group 0..15
  const int cu = blockIdx.x & 15;  // CU in group
  const int d0 = cu << 5;          // owned dim base (32 dims)
  unsigned* fl = flags + (g << 4);

  extern __shared__ float smem[];
  float* s_T = smem + L_ST;        // [j][256]
  float* s_sl = smem + L_SSL;      // [k][36]
  float* x_sl = smem + L_X;
  float* p_sl = smem + L_P;
  float* gi_sl = smem + L_GI;
  float* gh_sl = smem + L_GH;
  float* hc_sl = smem + L_HC;
  float* hp_sl = smem + L_HP;
  float* bih_sl = smem + L_BIH;
  float* bhh_sl = smem + L_BHH;
  float* d_sl = smem + L_D;

  const int wv = tid >> 6, lane = tid & 63;
  const int rowblk = tid >> 4, kseg = tid & 15;  // GEMM org: 32 rowblk x 16 kseg

  // ---- setup ----
  for (int e = tid; e < K_ * DPC; e += TPB) {
    int k = e >> 5, j = e & 31;
    float v = states[((size_t)k << 9) + d0 + j];
    s_T[j * 256 + k] = v;      // one-time conflicted write, amortized
    s_sl[k * 36 + j] = v;
  }
  if (tid < 96) {
    int grow = ((tid >> 5) << 9) + d0 + (tid & 31);
    bih_sl[tid] = bias_ih[grow];
    bhh_sl[tid] = bias_hh[grow];
  }
  if (tid < 128) {
    int b = tid >> 5, j = tid & 31;
    hp_sl[(b << 5) + j] = h0[((size_t)(g * NB + b) << 9) + d0 + j];
  }
  if (tid < 384) {
    int b = tid / 96, r = tid % 96;
    int grow = ((r >> 5) << 9) + d0 + (r & 31);
    gh_sl[b * 96 + r] = Gh0[(size_t)(g * NB + b) * G3H + grow];
  }
  // weight fragments -> registers: 3 rows x 16 k per thread, both matrices
  float4 wi[3][4], wh[3][4];
#pragma unroll
  for (int i = 0; i < 3; ++i) {
    int r = rowblk * 3 + i;  // 0..95
    int grow = ((r >> 5) << 9) + d0 + (r & 31);
    const float4* si = (const float4*)(W_ih + (size_t)grow * K_ + (kseg << 4));
    const float4* sh = (const float4*)(SWT + (size_t)grow * K_ + (kseg << 4));
    wi[i][0] = si[0]; wi[i][1] = si[1]; wi[i][2] = si[2]; wi[i][3] = si[3];
    wh[i][0] = sh[0]; wh[i][1] = sh[1]; wh[i][2] = sh[2]; wh[i][3] = sh[3];
  }
  __syncthreads();

  // ---- pre-loop: stage x(0), gi(0) ----
  if (tid < 256) {
    int b = tid >> 6, q = tid & 63;
    float4 v = *((const float4*)(input + ((size_t)(g * NB + b) * S_) * I_) + q);
    *(float4*)(x_sl + (b << 8) + (q << 2)) = v;
  }
  __syncthreads();
  {
    float acc[4][3] = {};
#pragma unroll
    for (int b = 0; b < 4; ++b) {
      const float4* xp = (const float4*)(x_sl + (b << 8) + (kseg << 4));
#pragma unroll
      for (int c = 0; c < 4; ++c) {
        float4 xv = xp[c];
#pragma unroll
        for (int i = 0; i < 3; ++i) acc[b][i] += dot4(wi[i][c], xv);
      }
    }
#pragma unroll
    for (int b = 0; b < 4; ++b)
#pragma unroll
      for (int i = 0; i < 3; ++i) {
        float v = acc[b][i];
        v += __shfl_xor(v, 1); v += __shfl_xor(v, 2);
        v += __shfl_xor(v, 4); v += __shfl_xor(v, 8);
        acc[b][i] = v;
      }
    if (kseg == 0) {
#pragma unroll
      for (int b = 0; b < 4; ++b)
#pragma unroll
        for (int i = 0; i < 3; ++i) gi_sl[b * 96 + rowblk * 3 + i] = acc[b][i];
    }
  }
  __syncthreads();

  for (int t = 0; t < S_; ++t) {
    const int slot = t & 1;
    float* pslot = part + ((size_t)(slot * NGRP + g) << 14);  // [16][4][256]

    // ---- A: gates + h_cand over owned 32 dims ----
    if (tid < 128) {
      int b = tid >> 5, j = tid & 31;
      float gir = gi_sl[b * 96 + j] + bih_sl[j];
      float giz = gi_sl[b * 96 + 32 + j] + bih_sl[32 + j];
      float gin = gi_sl[b * 96 + 64 + j] + bih_sl[64 + j];
      float ghr = gh_sl[b * 96 + j] + bhh_sl[j];
      float ghz = gh_sl[b * 96 + 32 + j] + bhh_sl[32 + j];
      float ghn = gh_sl[b * 96 + 64 + j] + bhh_sl[64 + j];
      float r = 1.f / (1.f + expf(-(gir + ghr)));
      float z = 1.f / (1.f + expf(-(giz + ghz)));
      float n = tanhf(gin + r * ghn);
      hc_sl[(b << 5) + j] = (1.f - z) * n + z * hp_sl[(b << 5) + j];
    }
    __syncthreads();

    // ---- B: dist partials. thread = (bp, k); scalar j-loop on s_T ----
    {
      int bp = tid >> 8, k = tid & 255;
      int b1 = bp << 1, b2 = b1 + 1;
      const float* h1 = hc_sl + (b1 << 5);
      const float* h2 = hc_sl + (b2 << 5);
      float a1 = 0.f, a2 = 0.f;
#pragma unroll
      for (int j = 0; j < DPC; ++j) {
        float sv = s_T[j * 256 + k];
        float e1 = h1[j] - sv; a1 += e1 * e1;
        float e2 = h2[j] - sv; a2 += e2 * e2;
      }
      __hip_atomic_store(pslot + (cu << 10) + (b1 << 8) + k, a1, RLX, AGENT);
      __hip_atomic_store(pslot + (cu << 10) + (b2 << 8) + k, a2, RLX, AGENT);
    }
    __syncthreads();  // drains vmcnt in all waves before release
    if (tid == 0)
      __hip_atomic_store(fl + cu, (unsigned)(t + 1), __ATOMIC_RELEASE, AGENT);

    // ---- C (barrier shadow): stage x(t+1) + gi(t+1) GEMM (register W_ih) ----
    if (t + 1 < S_) {
      if (tid < 256) {
        int b = tid >> 6, q = tid & 63;
        float4 v = *((const float4*)(input +
                     ((size_t)(g * NB + b) * S_ + (t + 1)) * I_) + q);
        *(float4*)(x_sl + (b << 8) + (q << 2)) = v;
      }
      __syncthreads();
      {
        float acc[4][3] = {};
#pragma unroll
        for (int b = 0; b < 4; ++b) {
          const float4* xp = (const float4*)(x_sl + (b << 8) + (kseg << 4));
#pragma unroll
          for (int c = 0; c < 4; ++c) {
            float4 xv = xp[c];
#pragma unroll
            for (int i = 0; i < 3; ++i) acc[b][i] += dot4(wi[i][c], xv);
          }
        }
#pragma unroll
        for (int b = 0; b < 4; ++b)
#pragma unroll
          for (int i = 0; i < 3; ++i) {
            float v = acc[b][i];
            v += __shfl_xor(v, 1); v += __shfl_xor(v, 2);
            v += __shfl_xor(v, 4); v += __shfl_xor(v, 8);
            acc[b][i] = v;
          }
        if (kseg == 0) {
#pragma unroll
          for (int b = 0; b < 4; ++b)
#pragma unroll
            for (int i = 0; i < 3; ++i)
              gi_sl[b * 96 + rowblk * 3 + i] = acc[b][i];
        }
      }
    }

    // ---- E: poll the 16 flags ----
    if (tid < GCU) {
      for (int it = 0; it < SPIN_MAX; ++it) {
        if (__hip_atomic_load(fl + tid, RLX, AGENT) >= (unsigned)(t + 1)) break;
        __builtin_amdgcn_s_sleep(1);
      }
    }
    __syncthreads();

    // ---- F: gather 16 partials (coalesced rows), sum -> d_sl ----
    {
      int bp = tid >> 8, k = tid & 255;
      int b1 = bp << 1, b2 = b1 + 1;
      const float* q1 = pslot + (b1 << 8) + k;
      const float* q2 = pslot + (b2 << 8) + k;
      float s1 = 0.f, s2 = 0.f;
#pragma unroll
      for (int c = 0; c < GCU; ++c) {
        s1 += __hip_atomic_load(q1 + (c << 10), RLX, AGENT);
        s2 += __hip_atomic_load(q2 + (c << 10), RLX, AGENT);
      }
      d_sl[(b1 << 8) + k] = s1;
      d_sl[(b2 << 8) + k] = s2;
    }
    __syncthreads();

    // ---- G: softmax (waves 0-3, wave = batch) -> p_sl + probs ----
    if (wv < NB) {
      int b = wv;
      const float* db = d_sl + (b << 8);
      float dd0 = db[lane], dd1 = db[lane + 64], dd2 = db[lane + 128],
            dd3 = db[lane + 192];
      float mn = fminf(fminf(dd0, dd1), fminf(dd2, dd3));
#pragma unroll
      for (int off = 32; off >= 1; off >>= 1) mn = fminf(mn, __shfl_xor(mn, off));
      float e0 = expf(mn - dd0), e1 = expf(mn - dd1), e2 = expf(mn - dd2),
            e3 = expf(mn - dd3);
      float s = (e0 + e1) + (e2 + e3);
#pragma unroll
      for (int off = 32; off >= 1; off >>= 1) s += __shfl_xor(s, off);
      float inv = 1.f / s;
      e0 *= inv; e1 *= inv; e2 *= inv; e3 *= inv;
      float* pb = p_sl + (b << 8);
      pb[lane] = e0; pb[lane + 64] = e1; pb[lane + 128] = e2; pb[lane + 192] = e3;
      if (cu == 0) {
        float* pr = probs + (((size_t)(g * NB + b) * S_ + t) << 8);
        pr[lane] = e0; pr[lane + 64] = e1; pr[lane + 128] = e2; pr[lane + 192] = e3;
      }
    }
    __syncthreads();

    // ---- H1: gh(t+1) = p @ SWT^T from registers ----
    if (t + 1 < S_) {
      float acc[4][3] = {};
#pragma unroll
      for (int b = 0; b < 4; ++b) {
        const float4* xp = (const float4*)(p_sl + (b << 8) + (kseg << 4));
#pragma unroll
        for (int c = 0; c < 4; ++c) {
          float4 xv = xp[c];
#pragma unroll
          for (int i = 0; i < 3; ++i) acc[b][i] += dot4(wh[i][c], xv);
        }
      }
#pragma unroll
      for (int b = 0; b < 4; ++b)
#pragma unroll
        for (int i = 0; i < 3; ++i) {
          float v = acc[b][i];
          v += __shfl_xor(v, 1); v += __shfl_xor(v, 2);
          v += __shfl_xor(v, 4); v += __shfl_xor(v, 8);
          acc[b][i] = v;
        }
      if (kseg == 0) {
#pragma unroll
        for (int b = 0; b < 4; ++b)
#pragma unroll
          for (int i = 0; i < 3; ++i)
            gh_sl[b * 96 + rowblk * 3 + i] = acc[b][i];
      }
    }

    // ---- H2: h_new over owned 32 dims; scalar k-loop on s_sl ----
    {
      int b = tid >> 7, j = (tid >> 2) & 31, kq = tid & 3;
      const float* pb = p_sl + (b << 8);
      float a = 0.f;
#pragma unroll
      for (int i = 0; i < 64; ++i) {
        int k = kq + (i << 2);
        a += pb[k] * s_sl[k * 36 + j];
      }
      a += __shfl_xor(a, 1);
      a += __shfl_xor(a, 2);
      if (kq == 0) {
        hp_sl[(b << 5) + j] = a;
        out[(((size_t)(g * NB + b) * S_ + t) << 9) + d0 + j] = a;
      }
    }
    __syncthreads();
  }

  // ---- final hidden state ----
  if (tid < 128) {
    int b = tid >> 5, j = tid & 31;
    hn[((size_t)(g * NB + b) << 9) + d0 + j] = hp_sl[(b << 5) + j];
  }
}

// ---------------------------------------------------------------------------
extern "C" void kernel_launch(void* const* d_in, const int* in_sizes, int n_in,
                              void* d_out, int out_size, void* d_ws,
                              size_t ws_size, hipStream_t stream) {
  const float* input = (const float*)d_in[0];
  const float* h0 = (const float*)d_in[1];
  const float* W_ih = (const float*)d_in[2];
  const float* W_hh = (const float*)d_in[3];
  const float* bias_ih = (const float*)d_in[4];
  const float* bias_hh = (const float*)d_in[5];
  const float* states = (const float*)d_in[6];
  float* out = (float*)d_out;

  char* ws = (char*)d_ws;
  unsigned int* flags = (unsigned int*)(ws + WS_FLAGS);
  float* SWT = (float*)(ws + WS_SWT);
  float* Gh0 = (float*)(ws + WS_GH0);
  float* part = (float*)(ws + WS_PART);

  (void)hipMemsetAsync(d_ws, 0, WS_FLAGS_SZ, stream);  // flags -> 0
  kernel_swt<<<G3H / 8, 256, 0, stream>>>(W_hh, states, SWT);
  kernel_gh0<<<B_, 256, 0, stream>>>(W_hh, h0, Gh0);

  (void)hipFuncSetAttribute(reinterpret_cast<const void*>(srrnn_main),
                            hipFuncAttributeMaxDynamicSharedMemorySize,
                            SMEM_BYTES);
  srrnn_main<<<NGRP * GCU, TPB, SMEM_BYTES, stream>>>(
      input, h0, W_ih, bias_ih, bias_hh, states, SWT, Gh0, part, flags,
      out, out + OUT_OFF_HN, out + OUT_OFF_P);
}